// Round 15
// baseline (43.815 us; speedup 1.0000x reference)
//
#include <hip/hip_runtime.h>
#include <hip/hip_bf16.h>
#include <math.h>

#define T_DIM 32
#define B_DIM 128
#define D_DIM 512
#define M_DIM 1024

constexpr float DT = 0.1875f;          // 3.0 / 16
constexpr float INV_2PI = 0.15915494309189535f;

typedef __attribute__((ext_vector_type(8))) short bf16x8;     // MFMA A/B operand
typedef __attribute__((ext_vector_type(4))) float f32x4;      // MFMA acc
typedef __attribute__((ext_vector_type(2))) float f32x2;      // packed (cos,sin)
typedef __attribute__((ext_vector_type(4))) unsigned u32x4;   // 8 packed bf16

// RNE fp32 pair -> packed bf16 word (lo = first arg). gfx950 v_cvt_pk_bf16_f32.
__device__ __forceinline__ unsigned cvtpk(float lo, float hi) {
    unsigned r;
    asm("v_cvt_pk_bf16_f32 %0, %1, %2" : "=v"(r) : "v"(lo), "v"(hi));
    return r;
}

// async global->LDS, 16B per lane; LDS dest is wave-uniform base + lane*16.
__device__ __forceinline__ void gload16(const void* g, void* l) {
    __builtin_amdgcn_global_load_lds(
        (const __attribute__((address_space(1))) void*)g,
        (__attribute__((address_space(3))) void*)l, 16, 0, 0);
}

// v_sin/v_cos take REVOLUTIONS (ISA: D=sin(S0*2pi)); reduce with floor.
__device__ __forceinline__ void fast_sincos(float theta, float& s, float& c) {
    float r = theta * INV_2PI;
    r -= floorf(r);
    s = __builtin_amdgcn_sinf(r);
    c = __builtin_amdgcn_cosf(r);
}

// CF machinery (validated R4/R14): Chebyshev rotation over 16 knots, named regs.
#define CHEB(CS) { const f32x2 nxt = c2 * cur - prev; prev = cur; cur = nxt; CS += cur; }
#define CF_ALL(V) { \
    float s1, c1; fast_sincos((V) * DT, s1, c1); \
    const float c2 = 2.0f * c1; \
    f32x2 prev = {1.0f, 0.0f}; \
    f32x2 cur  = {c1, s1}; \
    cs0 += cur; \
    CHEB(cs1)  CHEB(cs2)  CHEB(cs3)  CHEB(cs4)  CHEB(cs5) \
    CHEB(cs6)  CHEB(cs7)  CHEB(cs8)  CHEB(cs9)  CHEB(cs10) \
    CHEB(cs11) CHEB(cs12) CHEB(cs13) CHEB(cs14) CHEB(cs15) }
#define RED(CS) { \
    CS.x += __shfl_xor(CS.x, 16); CS.x += __shfl_xor(CS.x, 32); \
    CS.y += __shfl_xor(CS.y, 16); CS.y += __shfl_xor(CS.y, 32); }
#define ST(CS, K) { wred[wc][l15][K] = CS.x; wred[wc][l15][16 + K] = CS.y; }
#define FIN(CS, KK) { \
    constexpr float tk = DT * (float)(KK); \
    const float g  = __expf(-0.5f * tk * tk); \
    const float w  = (((KK) == 16) ? DT : 2.0f * DT) * g; \
    const float totC = wred[wc][l15][(KK) - 1]      + CS.x; \
    const float totS = wred[wc][l15][16 + (KK) - 1] + CS.y; \
    const float cm = fmaf(totC, invB, -g); \
    const float sm = totS * invB; \
    s = fmaf(w, fmaf(cm, cm, sm * sm), s); }

// ---------- MEGA: single launch. block = (128 m-cols, one t); 512 thr (8 waves 2x4).
// Phase 0: column norms (in-block). Phase 1: 8 K-tiles: z fp32 staged via swizzled
// gload16 + in-reg RNE cvt; B built direct from A (same k-mapping as validated path).
// Phase 2: validated CF epilogue, fn-split (32 VGPR CF state). One atomicAdd.
__global__ __launch_bounds__(512) void mega_kernel(const float* __restrict__ z,
                                                   const float* __restrict__ Amat,
                                                   float* __restrict__ out) {
    __shared__ __align__(16) float Asf[128 * 64];   // 32 KB fp32 z tile
    __shared__ float nred[16][128];                 // 8 KB norm partials
    __shared__ float inv[128];
    __shared__ float wred[4][16][33];               // 8.25 KB CF reduce
    __shared__ float bred[4];

    const int tid  = threadIdx.x;
    const int bx   = blockIdx.x;                    // 0..255
    // XCD-grouped mapping: linear%8 selects XCD-> give each XCD 4 whole t-slices.
    const int t    = (bx & 7) * 4 + ((bx >> 3) & 3);
    const int mB   = (bx >> 5) << 7;                // 0..896 step 128
    const int wave = tid >> 6;
    const int lane = tid & 63;
    const int wr   = wave >> 2;                     // 0..1  (64 b-rows each)
    const int wc   = wave & 3;                      // 0..3  (32 m-cols each)
    const int l15  = lane & 15;
    const int lhi  = lane >> 4;

    const float* zrow = z + (size_t)t * B_DIM * D_DIM;

    // ---- staging lane map (fp32, inverse-swizzled source; validated derivation) ----
    const int rl = lane >> 4;                       // row within 4-row gload group

    float bv[2][2][8];                              // B floats [fn][ks][e]
    const int bcol = mB + wc * 32 + l15;

#define STAGE(IT) { \
    _Pragma("unroll") \
    for (int j = 0; j < 4; ++j) { \
        const int r0  = wave * 16 + j * 4; \
        const int row = r0 + rl; \
        const int src = ((((lane & 15) >> 1) ^ (row & 7)) << 3) + ((lane & 1) << 2); \
        gload16(&zrow[(size_t)row * D_DIM + (IT) * 64 + src], &Asf[r0 * 64]); \
    } }

#define BLOAD(IT) { \
    _Pragma("unroll") \
    for (int fn = 0; fn < 2; ++fn) \
        _Pragma("unroll") \
        for (int ks = 0; ks < 2; ++ks) \
            _Pragma("unroll") \
            for (int e = 0; e < 8; ++e) \
                bv[fn][ks][e] = Amat[(size_t)((IT) * 64 + ks * 32 + lhi * 8 + e) * M_DIM \
                                     + bcol + fn * 16]; }

    STAGE(0) BLOAD(0)

    // ---- Phase 0: column norms (float4 over m) ----
    {
        const int mq = tid & 31;                    // m-quad
        const int g  = tid >> 5;                    // 0..15 (32 d each)
        float4 a4 = make_float4(0.f, 0.f, 0.f, 0.f);
#pragma unroll 8
        for (int i = 0; i < 32; ++i) {
            const float4 v = *reinterpret_cast<const float4*>(
                &Amat[(size_t)(g * 32 + i) * M_DIM + mB + mq * 4]);
            a4.x = fmaf(v.x, v.x, a4.x);
            a4.y = fmaf(v.y, v.y, a4.y);
            a4.z = fmaf(v.z, v.z, a4.z);
            a4.w = fmaf(v.w, v.w, a4.w);
        }
        *reinterpret_cast<float4*>(&nred[g][mq * 4]) = a4;
    }
    __syncthreads();
    if (tid < 128) {
        float tot = 0.f;
#pragma unroll
        for (int g = 0; g < 16; ++g) tot += nred[g][tid];
        inv[tid] = 1.0f / fmaxf(sqrtf(tot), 1e-12f);
    }
    __syncthreads();            // inv ready; barrier also drained STAGE(0)/BLOAD(0)

    const float iv0 = inv[wc * 32 + l15];
    const float iv1 = inv[wc * 32 + 16 + l15];

    f32x4 acc[4][2];
#pragma unroll
    for (int fm = 0; fm < 4; ++fm) {
        acc[fm][0] = (f32x4)(0.0f);
        acc[fm][1] = (f32x4)(0.0f);
    }

    const int swz = (l15 & 7) << 3;                 // read-side XOR (floats)

    // ---- Phase 1: K-loop ----
    for (int it = 0; ; ++it) {
#pragma unroll
        for (int ks = 0; ks < 2; ++ks) {
            u32x4 bw0, bw1;
            bw0.x = cvtpk(bv[0][ks][0] * iv0, bv[0][ks][1] * iv0);
            bw0.y = cvtpk(bv[0][ks][2] * iv0, bv[0][ks][3] * iv0);
            bw0.z = cvtpk(bv[0][ks][4] * iv0, bv[0][ks][5] * iv0);
            bw0.w = cvtpk(bv[0][ks][6] * iv0, bv[0][ks][7] * iv0);
            bw1.x = cvtpk(bv[1][ks][0] * iv1, bv[1][ks][1] * iv1);
            bw1.y = cvtpk(bv[1][ks][2] * iv1, bv[1][ks][3] * iv1);
            bw1.z = cvtpk(bv[1][ks][4] * iv1, bv[1][ks][5] * iv1);
            bw1.w = cvtpk(bv[1][ks][6] * iv1, bv[1][ks][7] * iv1);
            const bf16x8 bf0 = __builtin_bit_cast(bf16x8, bw0);
            const bf16x8 bf1 = __builtin_bit_cast(bf16x8, bw1);
            const int co = (ks * 32 + lhi * 8) ^ swz;
#pragma unroll
            for (int fm = 0; fm < 4; ++fm) {
                const int row = wr * 64 + fm * 16 + l15;
                const float4 lo = *reinterpret_cast<const float4*>(&Asf[row * 64 + co]);
                const float4 hi = *reinterpret_cast<const float4*>(&Asf[row * 64 + co + 4]);
                u32x4 aw;
                aw.x = cvtpk(lo.x, lo.y);
                aw.y = cvtpk(lo.z, lo.w);
                aw.z = cvtpk(hi.x, hi.y);
                aw.w = cvtpk(hi.z, hi.w);
                const bf16x8 af = __builtin_bit_cast(bf16x8, aw);
                acc[fm][0] = __builtin_amdgcn_mfma_f32_16x16x32_bf16(af, bf0, acc[fm][0], 0, 0, 0);
                acc[fm][1] = __builtin_amdgcn_mfma_f32_16x16x32_bf16(af, bf1, acc[fm][1], 0, 0, 0);
            }
        }
        if (it == 7) break;
        __syncthreads();                            // Asf readers done
        STAGE(it + 1) BLOAD(it + 1)
        __syncthreads();                            // drain -> next tile visible
    }

    // ---- Phase 2: CF, two fn rounds sharing cs regs + wred ----
    float s = 0.0f;
    const float invB = 1.0f / 128.0f;

#define CF_ROUND(FN) { \
    f32x2 cs0  = {0.f,0.f}, cs1  = {0.f,0.f}, cs2  = {0.f,0.f}, cs3  = {0.f,0.f}; \
    f32x2 cs4  = {0.f,0.f}, cs5  = {0.f,0.f}, cs6  = {0.f,0.f}, cs7  = {0.f,0.f}; \
    f32x2 cs8  = {0.f,0.f}, cs9  = {0.f,0.f}, cs10 = {0.f,0.f}, cs11 = {0.f,0.f}; \
    f32x2 cs12 = {0.f,0.f}, cs13 = {0.f,0.f}, cs14 = {0.f,0.f}, cs15 = {0.f,0.f}; \
    _Pragma("unroll") \
    for (int fm = 0; fm < 4; ++fm) { \
        const f32x4 av = acc[fm][FN]; \
        CF_ALL(av.x) CF_ALL(av.y) CF_ALL(av.z) CF_ALL(av.w) \
    } \
    RED(cs0)  RED(cs1)  RED(cs2)  RED(cs3)  RED(cs4)  RED(cs5)  RED(cs6)  RED(cs7) \
    RED(cs8)  RED(cs9)  RED(cs10) RED(cs11) RED(cs12) RED(cs13) RED(cs14) RED(cs15) \
    if (wr == 0 && lane < 16) { \
        ST(cs0, 0)   ST(cs1, 1)   ST(cs2, 2)   ST(cs3, 3) \
        ST(cs4, 4)   ST(cs5, 5)   ST(cs6, 6)   ST(cs7, 7) \
        ST(cs8, 8)   ST(cs9, 9)   ST(cs10, 10) ST(cs11, 11) \
        ST(cs12, 12) ST(cs13, 13) ST(cs14, 14) ST(cs15, 15) \
    } \
    __syncthreads(); \
    if (wr == 1) { \
        FIN(cs0, 1)   FIN(cs1, 2)   FIN(cs2, 3)   FIN(cs3, 4) \
        FIN(cs4, 5)   FIN(cs5, 6)   FIN(cs6, 7)   FIN(cs7, 8) \
        FIN(cs8, 9)   FIN(cs9, 10)  FIN(cs10, 11) FIN(cs11, 12) \
        FIN(cs12, 13) FIN(cs13, 14) FIN(cs14, 15) FIN(cs15, 16) \
    } \
    __syncthreads(); }

    CF_ROUND(0)
    CF_ROUND(1)

    if (wr == 1) {
        // butterfly over 64 lanes; each (fn,l15) column counted 4x (lhi copies)
#pragma unroll
        for (int m = 1; m < 64; m <<= 1) s += __shfl_xor(s, m);
        if (lane == 0) bred[wc] = s;
    }
    __syncthreads();
    // out = B * sum(stat-means) / (T*M): (1/4 dup) * 128 / 32768 = 1/1024
    if (tid == 0)
        atomicAdd(out, (bred[0] + bred[1] + bred[2] + bred[3]) * (1.0f / 1024.0f));
}

extern "C" void kernel_launch(void* const* d_in, const int* in_sizes, int n_in,
                              void* d_out, int out_size, void* d_ws, size_t ws_size,
                              hipStream_t stream) {
    const float* z = (const float*)d_in[0];   // (32,128,512) fp32
    const float* A = (const float*)d_in[1];   // (512,1024) fp32
    float* out = (float*)d_out;

    hipMemsetAsync(out, 0, sizeof(float), stream);   // atomics accumulate into out[0]
    mega_kernel<<<256, 512, 0, stream>>>(z, A, out);
}

// Round 16
// 39.459 us; speedup vs baseline: 1.1104x; 1.1104x over previous
//
#include <hip/hip_runtime.h>
#include <hip/hip_bf16.h>
#include <math.h>

#define T_DIM 32
#define B_DIM 128
#define D_DIM 512
#define M_DIM 1024

constexpr float DT = 0.1875f;          // 3.0 / 16
constexpr float INV_2PI = 0.15915494309189535f;

typedef __attribute__((ext_vector_type(8))) short bf16x8;   // 8 bf16 = 4 VGPR
typedef __attribute__((ext_vector_type(4))) float f32x4;    // MFMA acc
typedef __attribute__((ext_vector_type(2))) float f32x2;    // packed (cos,sin)

__device__ __forceinline__ ushort f2bf(float f) {           // RNE fp32->bf16
    unsigned u = __float_as_uint(f);
    u += 0x7FFFu + ((u >> 16) & 1u);
    return (ushort)(u >> 16);
}

// async global->LDS, 16B per lane; LDS dest is wave-uniform base + lane*16.
__device__ __forceinline__ void gload16(const void* g, void* l) {
    __builtin_amdgcn_global_load_lds(
        (const __attribute__((address_space(1))) void*)g,
        (__attribute__((address_space(3))) void*)l, 16, 0, 0);
}

// v_sin/v_cos take REVOLUTIONS (ISA: D=sin(S0*2pi)); reduce with floor.
__device__ __forceinline__ void fast_sincos(float theta, float& s, float& c) {
    float r = theta * INV_2PI;
    r -= floorf(r);
    s = __builtin_amdgcn_sinf(r);
    c = __builtin_amdgcn_cosf(r);
}

// ---------- K1: prep (validated R8-R14). blocks 0..63: colnorm+transpose -> ant.
//                blocks 64..319: z -> bf16. block 0 zeroes out[0]. ----------
__global__ __launch_bounds__(256) void prep_kernel(const float* __restrict__ A,
                                                   const float* __restrict__ z,
                                                   ushort* __restrict__ zb,
                                                   ushort* __restrict__ ant,
                                                   float* __restrict__ out) {
    const int bid = blockIdx.x;
    const int tid = threadIdx.x;

    if (bid >= 64) {                       // ---- zconv: 256 blocks x 8192 floats ----
        const size_t base = (size_t)(bid - 64) * 8192 + tid * 8;
#pragma unroll
        for (int j = 0; j < 4; ++j) {
            const size_t i = base + j * 2048;
            const float4 a = *reinterpret_cast<const float4*>(&z[i]);
            const float4 b = *reinterpret_cast<const float4*>(&z[i + 4]);
            uint4 p;
            p.x = (unsigned)f2bf(a.x) | ((unsigned)f2bf(a.y) << 16);
            p.y = (unsigned)f2bf(a.z) | ((unsigned)f2bf(a.w) << 16);
            p.z = (unsigned)f2bf(b.x) | ((unsigned)f2bf(b.y) << 16);
            p.w = (unsigned)f2bf(b.z) | ((unsigned)f2bf(b.w) << 16);
            *reinterpret_cast<uint4*>(&zb[i]) = p;
        }
        return;
    }

    if (bid == 0 && tid == 0) out[0] = 0.0f;   // reset accumulator for atomics

    __shared__ float red[256];
    __shared__ float inv[16];
    __shared__ float tile[128][17];

    const int mB = bid * 16;
    const int mo = tid & 15;
    const int dg = tid >> 4;
    float ss = 0.0f;
#pragma unroll 4
    for (int i = 0; i < 32; ++i) {
        const float v = A[(size_t)(dg * 32 + i) * M_DIM + mB + mo];
        ss = fmaf(v, v, ss);
    }
    red[tid] = ss;
    __syncthreads();
    for (int s = 128; s >= 16; s >>= 1) {
        if (tid < s) red[tid] += red[tid + s];
        __syncthreads();
    }
    if (tid < 16) inv[tid] = 1.0f / fmaxf(sqrtf(red[tid]), 1e-12f);

#pragma unroll
    for (int ch = 0; ch < 4; ++ch) {
        const int dB = ch * 128;
#pragma unroll
        for (int q = 0; q < 2; ++q) {
            const int s  = tid + 256 * q;
            const int r  = s >> 2;
            const int c4 = (s & 3) * 4;
            const float4 v = *reinterpret_cast<const float4*>(
                &A[(size_t)(dB + r) * M_DIM + mB + c4]);
            tile[r][c4]     = v.x;
            tile[r][c4 + 1] = v.y;
            tile[r][c4 + 2] = v.z;
            tile[r][c4 + 3] = v.w;
        }
        __syncthreads();
        {
            const int m  = tid >> 4;
            const int d8 = (tid & 15) * 8;
            const float sc = inv[m];
            uint4 p;
            p.x = (unsigned)f2bf(tile[d8 + 0][m] * sc) | ((unsigned)f2bf(tile[d8 + 1][m] * sc) << 16);
            p.y = (unsigned)f2bf(tile[d8 + 2][m] * sc) | ((unsigned)f2bf(tile[d8 + 3][m] * sc) << 16);
            p.z = (unsigned)f2bf(tile[d8 + 4][m] * sc) | ((unsigned)f2bf(tile[d8 + 5][m] * sc) << 16);
            p.w = (unsigned)f2bf(tile[d8 + 6][m] * sc) | ((unsigned)f2bf(tile[d8 + 7][m] * sc) << 16);
            *reinterpret_cast<uint4*>(&ant[(size_t)(mB + m) * D_DIM + dB + d8]) = p;
        }
        __syncthreads();
    }
}

// ---------- K2: fused GEMM+CF, double-buffered ONE-barrier K-loop + XCD mapping ----------
// Tile 128 b x 32 m; 1024 blocks (XCD-grouped: each XCD's 128 blocks share 4 t-slices).
// STAGE(it+1) issued BEFORE compute of it -> L2 latency hides under ds_read+MFMA;
// __syncthreads() at iter end drains both (vmcnt for stage, lgkm for frag reads).
#define CHEB(CS) { const f32x2 nxt = c2 * cur - prev; prev = cur; cur = nxt; CS += cur; }
#define CF_ALL(V) { \
    float s1, c1; fast_sincos((V) * DT, s1, c1); \
    const float c2 = 2.0f * c1; \
    f32x2 prev = {1.0f, 0.0f}; \
    f32x2 cur  = {c1, s1}; \
    cs0 += cur; \
    CHEB(cs1)  CHEB(cs2)  CHEB(cs3)  CHEB(cs4)  CHEB(cs5) \
    CHEB(cs6)  CHEB(cs7)  CHEB(cs8)  CHEB(cs9)  CHEB(cs10) \
    CHEB(cs11) CHEB(cs12) CHEB(cs13) CHEB(cs14) CHEB(cs15) }
#define RED(CS) { \
    CS.x += __shfl_xor(CS.x, 16); CS.x += __shfl_xor(CS.x, 32); \
    CS.y += __shfl_xor(CS.y, 16); CS.y += __shfl_xor(CS.y, 32); }
#define ST(CS, K) { wred[wc][l15][K] = CS.x; wred[wc][l15][16 + K] = CS.y; }
#define FIN(CS, KK) { \
    constexpr float tk = DT * (float)(KK); \
    const float g  = __expf(-0.5f * tk * tk); \
    const float w  = (((KK) == 16) ? DT : 2.0f * DT) * g; \
    const float totC = wred[wc][l15][(KK) - 1]      + CS.x; \
    const float totS = wred[wc][l15][16 + (KK) - 1] + CS.y; \
    const float cm = fmaf(totC, invB, -g); \
    const float sm = totS * invB; \
    s = fmaf(w, fmaf(cm, cm, sm * sm), s); }

__global__ __launch_bounds__(256) void fused_kernel(const ushort* __restrict__ zb,
                                                    const ushort* __restrict__ ant,
                                                    float* __restrict__ out) {
    __shared__ __align__(16) ushort As[2][128 * 64];   // 32 KB double-buffered
    __shared__ __align__(16) ushort Bs[2][32 * 64];    // 8 KB
    __shared__ float wred[2][16][33];
    __shared__ float bred[2];

    const int tid = threadIdx.x;
    // XCD-grouped bijective mapping (1024 blocks, 8 XCDs x 128):
    //   xcd = bid&7 ; idx = bid>>3 ; t = xcd*4 + (idx&3) ; mB = (idx>>2)*32
    const int bid = blockIdx.x;
    const int t   = (bid & 7) * 4 + ((bid >> 3) & 3);
    const int mB  = (bid >> 5) * 32;

    const int wave = tid >> 6;
    const int lane = tid & 63;
    const int wr   = wave >> 1;                     // b-row half
    const int wc   = wave & 1;                      // m-col half
    const int l15  = lane & 15;
    const int lhi  = lane >> 4;

    const int l8 = lane >> 3;              // 0..7 = dest row & 7
    const int cx = ((lane & 7) ^ l8) * 8;  // pre-swizzled source k-chunk (R13-validated)

    const ushort* zrow = zb + (size_t)t * B_DIM * D_DIM;

    f32x4 acc[4];
#pragma unroll
    for (int fm = 0; fm < 4; ++fm) acc[fm] = (f32x4)(0.0f);

    const int swz = (l15 & 7) * 8;         // read-side XOR

#define STAGE(IT, BUF) { \
    _Pragma("unroll") \
    for (int j = 0; j < 4; ++j) { \
        const int r0 = wave * 32 + j * 8; \
        gload16(&zrow[(size_t)(r0 + l8) * D_DIM + (IT) * 64 + cx], &As[BUF][r0 * 64]); \
    } \
    { \
        const int r0 = wave * 8; \
        gload16(&ant[(size_t)(mB + r0 + l8) * D_DIM + (IT) * 64 + cx], &Bs[BUF][r0 * 64]); \
    } }

    STAGE(0, 0)
    __syncthreads();                       // drain prologue stage

#pragma unroll
    for (int it = 0; it < 8; ++it) {
        const int cur = it & 1;
        if (it < 7) STAGE(it + 1, cur ^ 1)          // issue-early: overlaps compute below

#pragma unroll
        for (int ks = 0; ks < 2; ++ks) {
            const int co = (ks * 32 + lhi * 8) ^ swz;
            const bf16x8 bfrag = *reinterpret_cast<const bf16x8*>(&Bs[cur][(wc * 16 + l15) * 64 + co]);
#pragma unroll
            for (int fm = 0; fm < 4; ++fm) {
                const bf16x8 afrag = *reinterpret_cast<const bf16x8*>(&As[cur][(wr * 64 + fm * 16 + l15) * 64 + co]);
                acc[fm] = __builtin_amdgcn_mfma_f32_16x16x32_bf16(afrag, bfrag, acc[fm], 0, 0, 0);
            }
        }
        __syncthreads();   // drains: my frag reads (lgkm) + next-tile stage (vmcnt)
    }

    // ---- CF: per lane m = mB + wc*16 + l15 fixed; 16 b-values in acc (R4/R14 validated) ----
    f32x2 cs0  = {0.f, 0.f}, cs1  = {0.f, 0.f}, cs2  = {0.f, 0.f}, cs3  = {0.f, 0.f};
    f32x2 cs4  = {0.f, 0.f}, cs5  = {0.f, 0.f}, cs6  = {0.f, 0.f}, cs7  = {0.f, 0.f};
    f32x2 cs8  = {0.f, 0.f}, cs9  = {0.f, 0.f}, cs10 = {0.f, 0.f}, cs11 = {0.f, 0.f};
    f32x2 cs12 = {0.f, 0.f}, cs13 = {0.f, 0.f}, cs14 = {0.f, 0.f}, cs15 = {0.f, 0.f};

#pragma unroll
    for (int fm = 0; fm < 4; ++fm) {
        const f32x4 av = acc[fm];
        CF_ALL(av.x) CF_ALL(av.y) CF_ALL(av.z) CF_ALL(av.w)
    }

    RED(cs0)  RED(cs1)  RED(cs2)  RED(cs3)  RED(cs4)  RED(cs5)  RED(cs6)  RED(cs7)
    RED(cs8)  RED(cs9)  RED(cs10) RED(cs11) RED(cs12) RED(cs13) RED(cs14) RED(cs15)

    if (wr == 0 && lane < 16) {
        ST(cs0, 0)   ST(cs1, 1)   ST(cs2, 2)   ST(cs3, 3)
        ST(cs4, 4)   ST(cs5, 5)   ST(cs6, 6)   ST(cs7, 7)
        ST(cs8, 8)   ST(cs9, 9)   ST(cs10, 10) ST(cs11, 11)
        ST(cs12, 12) ST(cs13, 13) ST(cs14, 14) ST(cs15, 15)
    }
    __syncthreads();

    if (wr == 1) {
        const float invB = 1.0f / 128.0f;
        float s = 0.0f;
        FIN(cs0, 1)   FIN(cs1, 2)   FIN(cs2, 3)   FIN(cs3, 4)
        FIN(cs4, 5)   FIN(cs5, 6)   FIN(cs6, 7)   FIN(cs7, 8)
        FIN(cs8, 9)   FIN(cs9, 10)  FIN(cs10, 11) FIN(cs11, 12)
        FIN(cs12, 13) FIN(cs13, 14) FIN(cs14, 15) FIN(cs15, 16)
        // butterfly over 64 lanes: each l15 column counted 4x (lhi copies)
#pragma unroll
        for (int m = 1; m < 64; m <<= 1) s += __shfl_xor(s, m);
        if (lane == 0) bred[wc] = s;
    }
    __syncthreads();
    // out = (1/(T*M)) * B * stat-sum: (0.25 dup) * 128 / 32768 = 1/1024
    if (tid == 0)
        atomicAdd(out, (bred[0] + bred[1]) * (1.0f / 1024.0f));
}

extern "C" void kernel_launch(void* const* d_in, const int* in_sizes, int n_in,
                              void* d_out, int out_size, void* d_ws, size_t ws_size,
                              hipStream_t stream) {
    const float* z = (const float*)d_in[0];   // (32,128,512)
    const float* A = (const float*)d_in[1];   // (512,1024)
    float* out = (float*)d_out;

    char* ws = (char*)d_ws;
    ushort* zb  = (ushort*)ws;                        // 4 MB
    ushort* ant = (ushort*)(ws + 4 * 1024 * 1024);    // 1 MB

    prep_kernel<<<320, 256, 0, stream>>>(A, z, zb, ant, out);
    fused_kernel<<<1024, 256, 0, stream>>>(zb, ant, out);
}

// Round 17
// 32.185 us; speedup vs baseline: 1.3613x; 1.2260x over previous
//
#include <hip/hip_runtime.h>
#include <hip/hip_bf16.h>
#include <math.h>

#define T_DIM 32
#define B_DIM 128
#define D_DIM 512
#define M_DIM 1024

constexpr float DT = 0.1875f;          // 3.0 / 16
constexpr float INV_2PI = 0.15915494309189535f;

typedef __attribute__((ext_vector_type(8))) short bf16x8;   // 8 bf16 = 4 VGPR
typedef __attribute__((ext_vector_type(4))) float f32x4;    // MFMA acc
typedef __attribute__((ext_vector_type(2))) float f32x2;    // packed (cos,sin)

__device__ __forceinline__ ushort f2bf(float f) {           // RNE fp32->bf16
    unsigned u = __float_as_uint(f);
    u += 0x7FFFu + ((u >> 16) & 1u);
    return (ushort)(u >> 16);
}

// async global->LDS, 16B per lane; LDS dest is wave-uniform base + lane*16.
__device__ __forceinline__ void gload16(const void* g, void* l) {
    __builtin_amdgcn_global_load_lds(
        (const __attribute__((address_space(1))) void*)g,
        (__attribute__((address_space(3))) void*)l, 16, 0, 0);
}

// v_sin/v_cos take REVOLUTIONS (ISA: D=sin(S0*2pi)); reduce with floor.
__device__ __forceinline__ void fast_sincos(float theta, float& s, float& c) {
    float r = theta * INV_2PI;
    r -= floorf(r);
    s = __builtin_amdgcn_sinf(r);
    c = __builtin_amdgcn_cosf(r);
}

// ---------- K1: prep (validated R8-R16). blocks 0..63: colnorm+transpose -> ant.
//                blocks 64..319: z -> bf16. ----------
__global__ __launch_bounds__(256) void prep_kernel(const float* __restrict__ A,
                                                   const float* __restrict__ z,
                                                   ushort* __restrict__ zb,
                                                   ushort* __restrict__ ant) {
    const int bid = blockIdx.x;
    const int tid = threadIdx.x;

    if (bid >= 64) {                       // ---- zconv: 256 blocks x 8192 floats ----
        const size_t base = (size_t)(bid - 64) * 8192 + tid * 8;
#pragma unroll
        for (int j = 0; j < 4; ++j) {
            const size_t i = base + j * 2048;
            const float4 a = *reinterpret_cast<const float4*>(&z[i]);
            const float4 b = *reinterpret_cast<const float4*>(&z[i + 4]);
            uint4 p;
            p.x = (unsigned)f2bf(a.x) | ((unsigned)f2bf(a.y) << 16);
            p.y = (unsigned)f2bf(a.z) | ((unsigned)f2bf(a.w) << 16);
            p.z = (unsigned)f2bf(b.x) | ((unsigned)f2bf(b.y) << 16);
            p.w = (unsigned)f2bf(b.z) | ((unsigned)f2bf(b.w) << 16);
            *reinterpret_cast<uint4*>(&zb[i]) = p;
        }
        return;
    }

    __shared__ float red[256];
    __shared__ float inv[16];
    __shared__ float tile[128][17];

    const int mB = bid * 16;
    const int mo = tid & 15;
    const int dg = tid >> 4;
    float ss = 0.0f;
#pragma unroll 4
    for (int i = 0; i < 32; ++i) {
        const float v = A[(size_t)(dg * 32 + i) * M_DIM + mB + mo];
        ss = fmaf(v, v, ss);
    }
    red[tid] = ss;
    __syncthreads();
    for (int s = 128; s >= 16; s >>= 1) {
        if (tid < s) red[tid] += red[tid + s];
        __syncthreads();
    }
    if (tid < 16) inv[tid] = 1.0f / fmaxf(sqrtf(red[tid]), 1e-12f);

#pragma unroll
    for (int ch = 0; ch < 4; ++ch) {
        const int dB = ch * 128;
#pragma unroll
        for (int q = 0; q < 2; ++q) {
            const int s  = tid + 256 * q;
            const int r  = s >> 2;
            const int c4 = (s & 3) * 4;
            const float4 v = *reinterpret_cast<const float4*>(
                &A[(size_t)(dB + r) * M_DIM + mB + c4]);
            tile[r][c4]     = v.x;
            tile[r][c4 + 1] = v.y;
            tile[r][c4 + 2] = v.z;
            tile[r][c4 + 3] = v.w;
        }
        __syncthreads();
        {
            const int m  = tid >> 4;
            const int d8 = (tid & 15) * 8;
            const float sc = inv[m];
            uint4 p;
            p.x = (unsigned)f2bf(tile[d8 + 0][m] * sc) | ((unsigned)f2bf(tile[d8 + 1][m] * sc) << 16);
            p.y = (unsigned)f2bf(tile[d8 + 2][m] * sc) | ((unsigned)f2bf(tile[d8 + 3][m] * sc) << 16);
            p.z = (unsigned)f2bf(tile[d8 + 4][m] * sc) | ((unsigned)f2bf(tile[d8 + 5][m] * sc) << 16);
            p.w = (unsigned)f2bf(tile[d8 + 6][m] * sc) | ((unsigned)f2bf(tile[d8 + 7][m] * sc) << 16);
            *reinterpret_cast<uint4*>(&ant[(size_t)(mB + m) * D_DIM + dB + d8]) = p;
        }
        __syncthreads();
    }
}

// ---------- K2: fused GEMM+CF (R14 structure, best) — atomic replaced by plain store ----
// Tile 128 b x 32 m; grid (32 m, 32 t); 24.5 KB LDS -> all 1024 blocks co-resident.
// Same-address atomicAdd tail (~1024 serialized cross-XCD RMWs) was the hidden ~25 us:
// now each block does ONE uncontended store to partials[bid]; K3 reduces.
#define CHEB(CS) { const f32x2 nxt = c2 * cur - prev; prev = cur; cur = nxt; CS += cur; }
#define CF_ALL(V) { \
    float s1, c1; fast_sincos((V) * DT, s1, c1); \
    const float c2 = 2.0f * c1; \
    f32x2 prev = {1.0f, 0.0f}; \
    f32x2 cur  = {c1, s1}; \
    cs0 += cur; \
    CHEB(cs1)  CHEB(cs2)  CHEB(cs3)  CHEB(cs4)  CHEB(cs5) \
    CHEB(cs6)  CHEB(cs7)  CHEB(cs8)  CHEB(cs9)  CHEB(cs10) \
    CHEB(cs11) CHEB(cs12) CHEB(cs13) CHEB(cs14) CHEB(cs15) }
#define RED(CS) { \
    CS.x += __shfl_xor(CS.x, 16); CS.x += __shfl_xor(CS.x, 32); \
    CS.y += __shfl_xor(CS.y, 16); CS.y += __shfl_xor(CS.y, 32); }
#define ST(CS, K) { wred[wc][l15][K] = CS.x; wred[wc][l15][16 + K] = CS.y; }
#define FIN(CS, KK) { \
    constexpr float tk = DT * (float)(KK); \
    const float g  = __expf(-0.5f * tk * tk); \
    const float w  = (((KK) == 16) ? DT : 2.0f * DT) * g; \
    const float totC = wred[wc][l15][(KK) - 1]      + CS.x; \
    const float totS = wred[wc][l15][16 + (KK) - 1] + CS.y; \
    const float cm = fmaf(totC, invB, -g); \
    const float sm = totS * invB; \
    s = fmaf(w, fmaf(cm, cm, sm * sm), s); }

__global__ __launch_bounds__(256) void fused_kernel(const ushort* __restrict__ zb,
                                                    const ushort* __restrict__ ant,
                                                    float* __restrict__ partials) {
    __shared__ __align__(16) ushort As[128 * 64];   // 16 KB linear (gload_lds dest)
    __shared__ __align__(16) ushort Bs[32 * 64];    // 4 KB
    __shared__ float wred[2][16][33];               // [wc][m][k | 16+k], padded
    __shared__ float bred[2];

    const int tid  = threadIdx.x;
    const int mB   = blockIdx.x * 32;               // 32 m-blocks
    const int t    = blockIdx.y;                    // 0..31
    const int wave = tid >> 6;
    const int lane = tid & 63;
    const int wr   = wave >> 1;                     // b-row half
    const int wc   = wave & 1;                      // m-col half
    const int l15  = lane & 15;
    const int lhi  = lane >> 4;

    const int l8 = lane >> 3;              // 0..7 = dest row & 7
    const int cx = ((lane & 7) ^ l8) * 8;  // pre-swizzled source k-chunk (R13-validated)

    const ushort* zrow = zb + (size_t)t * B_DIM * D_DIM;

    f32x4 acc[4];
#pragma unroll
    for (int fm = 0; fm < 4; ++fm) acc[fm] = (f32x4)(0.0f);

    const int swz = (l15 & 7) * 8;         // read-side XOR

#pragma unroll
    for (int it = 0; it < 8; ++it) {
        const int k0 = it * 64;
#pragma unroll
        for (int j = 0; j < 4; ++j) {
            const int r0 = wave * 32 + j * 8;
            gload16(&zrow[(size_t)(r0 + l8) * D_DIM + k0 + cx], &As[r0 * 64]);
        }
        {
            const int r0 = wave * 8;
            gload16(&ant[(size_t)(mB + r0 + l8) * D_DIM + k0 + cx], &Bs[r0 * 64]);
        }
        __syncthreads();                   // drains vmcnt -> LDS visible

#pragma unroll
        for (int ks = 0; ks < 2; ++ks) {
            const int co = (ks * 32 + lhi * 8) ^ swz;
            const bf16x8 bfrag = *reinterpret_cast<const bf16x8*>(&Bs[(wc * 16 + l15) * 64 + co]);
#pragma unroll
            for (int fm = 0; fm < 4; ++fm) {
                const bf16x8 afrag = *reinterpret_cast<const bf16x8*>(&As[(wr * 64 + fm * 16 + l15) * 64 + co]);
                acc[fm] = __builtin_amdgcn_mfma_f32_16x16x32_bf16(afrag, bfrag, acc[fm], 0, 0, 0);
            }
        }
        __syncthreads();                   // readers done before next overwrite
    }

    // ---- CF: per lane m = mB + wc*16 + l15 fixed; 16 b-values in acc (validated) ----
    f32x2 cs0  = {0.f, 0.f}, cs1  = {0.f, 0.f}, cs2  = {0.f, 0.f}, cs3  = {0.f, 0.f};
    f32x2 cs4  = {0.f, 0.f}, cs5  = {0.f, 0.f}, cs6  = {0.f, 0.f}, cs7  = {0.f, 0.f};
    f32x2 cs8  = {0.f, 0.f}, cs9  = {0.f, 0.f}, cs10 = {0.f, 0.f}, cs11 = {0.f, 0.f};
    f32x2 cs12 = {0.f, 0.f}, cs13 = {0.f, 0.f}, cs14 = {0.f, 0.f}, cs15 = {0.f, 0.f};

#pragma unroll
    for (int fm = 0; fm < 4; ++fm) {
        const f32x4 av = acc[fm];
        CF_ALL(av.x) CF_ALL(av.y) CF_ALL(av.z) CF_ALL(av.w)
    }

    RED(cs0)  RED(cs1)  RED(cs2)  RED(cs3)  RED(cs4)  RED(cs5)  RED(cs6)  RED(cs7)
    RED(cs8)  RED(cs9)  RED(cs10) RED(cs11) RED(cs12) RED(cs13) RED(cs14) RED(cs15)

    if (wr == 0 && lane < 16) {
        ST(cs0, 0)   ST(cs1, 1)   ST(cs2, 2)   ST(cs3, 3)
        ST(cs4, 4)   ST(cs5, 5)   ST(cs6, 6)   ST(cs7, 7)
        ST(cs8, 8)   ST(cs9, 9)   ST(cs10, 10) ST(cs11, 11)
        ST(cs12, 12) ST(cs13, 13) ST(cs14, 14) ST(cs15, 15)
    }
    __syncthreads();

    if (wr == 1) {
        const float invB = 1.0f / 128.0f;
        float s = 0.0f;
        FIN(cs0, 1)   FIN(cs1, 2)   FIN(cs2, 3)   FIN(cs3, 4)
        FIN(cs4, 5)   FIN(cs5, 6)   FIN(cs6, 7)   FIN(cs7, 8)
        FIN(cs8, 9)   FIN(cs9, 10)  FIN(cs10, 11) FIN(cs11, 12)
        FIN(cs12, 13) FIN(cs13, 14) FIN(cs14, 15) FIN(cs15, 16)
        // butterfly over 64 lanes: each l15 column counted 4x (lhi copies)
#pragma unroll
        for (int m = 1; m < 64; m <<= 1) s += __shfl_xor(s, m);
        if (lane == 0) bred[wc] = s;
    }
    __syncthreads();
    // plain uncontended store; scale folded into finalize
    if (tid == 0)
        partials[blockIdx.y * 32 + blockIdx.x] = bred[0] + bred[1];
}

// ---------- K3: final reduce of 1024 partials ----------
// out = sum(partials) * (0.25 dup) * 128 / (T*M) = sum / 1024
__global__ __launch_bounds__(256) void finalize_kernel(const float* __restrict__ partials,
                                                       float* __restrict__ out) {
    __shared__ float red[256];
    const int tid = threadIdx.x;
    red[tid] = partials[tid] + partials[tid + 256] + partials[tid + 512] + partials[tid + 768];
    __syncthreads();
    for (int s = 128; s > 0; s >>= 1) {
        if (tid < s) red[tid] += red[tid + s];
        __syncthreads();
    }
    if (tid == 0) out[0] = red[0] * (1.0f / 1024.0f);
}

extern "C" void kernel_launch(void* const* d_in, const int* in_sizes, int n_in,
                              void* d_out, int out_size, void* d_ws, size_t ws_size,
                              hipStream_t stream) {
    const float* z = (const float*)d_in[0];   // (32,128,512)
    const float* A = (const float*)d_in[1];   // (512,1024)
    float* out = (float*)d_out;

    char* ws = (char*)d_ws;
    ushort* zb       = (ushort*)ws;                        // 4 MB
    ushort* ant      = (ushort*)(ws + 4 * 1024 * 1024);    // 1 MB
    float*  partials = (float*)(ws + 5 * 1024 * 1024);     // 4 KB

    prep_kernel<<<320, 256, 0, stream>>>(A, z, zb, ant);
    fused_kernel<<<dim3(M_DIM / 32, T_DIM), 256, 0, stream>>>(zb, ant, partials);
    finalize_kernel<<<1, 256, 0, stream>>>(partials, out);
}

// Round 18
// 31.590 us; speedup vs baseline: 1.3870x; 1.0188x over previous
//
#include <hip/hip_runtime.h>
#include <hip/hip_bf16.h>
#include <math.h>

#define T_DIM 32
#define B_DIM 128
#define D_DIM 512
#define M_DIM 1024

constexpr float DT = 0.1875f;          // 3.0 / 16
constexpr float INV_2PI = 0.15915494309189535f;

typedef __attribute__((ext_vector_type(8))) short bf16x8;   // 8 bf16 = 4 VGPR
typedef __attribute__((ext_vector_type(4))) float f32x4;    // MFMA acc
typedef __attribute__((ext_vector_type(2))) float f32x2;    // packed (cos,sin)

__device__ __forceinline__ ushort f2bf(float f) {           // RNE fp32->bf16
    unsigned u = __float_as_uint(f);
    u += 0x7FFFu + ((u >> 16) & 1u);
    return (ushort)(u >> 16);
}

// async global->LDS, 16B per lane; LDS dest is wave-uniform base + lane*16.
__device__ __forceinline__ void gload16(const void* g, void* l) {
    __builtin_amdgcn_global_load_lds(
        (const __attribute__((address_space(1))) void*)g,
        (__attribute__((address_space(3))) void*)l, 16, 0, 0);
}

// v_sin/v_cos take REVOLUTIONS (ISA: D=sin(S0*2pi)); reduce with floor.
__device__ __forceinline__ void fast_sincos(float theta, float& s, float& c) {
    float r = theta * INV_2PI;
    r -= floorf(r);
    s = __builtin_amdgcn_sinf(r);
    c = __builtin_amdgcn_cosf(r);
}

// ---------- K1: prep. blocks 0..63: colnorm+transpose -> ant (validated R8-R17).
//                blocks 64..575: z -> bf16 (widened: 512 blocks, 2 blk/CU). ----------
__global__ __launch_bounds__(256) void prep_kernel(const float* __restrict__ A,
                                                   const float* __restrict__ z,
                                                   ushort* __restrict__ zb,
                                                   ushort* __restrict__ ant) {
    const int bid = blockIdx.x;
    const int tid = threadIdx.x;

    if (bid >= 64) {                       // ---- zconv: 512 blocks x 4096 floats ----
        const size_t base = (size_t)(bid - 64) * 4096 + tid * 8;
#pragma unroll
        for (int j = 0; j < 2; ++j) {
            const size_t i = base + j * 2048;
            const float4 a = *reinterpret_cast<const float4*>(&z[i]);
            const float4 b = *reinterpret_cast<const float4*>(&z[i + 4]);
            uint4 p;
            p.x = (unsigned)f2bf(a.x) | ((unsigned)f2bf(a.y) << 16);
            p.y = (unsigned)f2bf(a.z) | ((unsigned)f2bf(a.w) << 16);
            p.z = (unsigned)f2bf(b.x) | ((unsigned)f2bf(b.y) << 16);
            p.w = (unsigned)f2bf(b.z) | ((unsigned)f2bf(b.w) << 16);
            *reinterpret_cast<uint4*>(&zb[i]) = p;
        }
        return;
    }

    __shared__ float red[256];
    __shared__ float inv[16];
    __shared__ float tile[128][17];

    const int mB = bid * 16;
    const int mo = tid & 15;
    const int dg = tid >> 4;
    float ss = 0.0f;
#pragma unroll 4
    for (int i = 0; i < 32; ++i) {
        const float v = A[(size_t)(dg * 32 + i) * M_DIM + mB + mo];
        ss = fmaf(v, v, ss);
    }
    red[tid] = ss;
    __syncthreads();
    for (int s = 128; s >= 16; s >>= 1) {
        if (tid < s) red[tid] += red[tid + s];
        __syncthreads();
    }
    if (tid < 16) inv[tid] = 1.0f / fmaxf(sqrtf(red[tid]), 1e-12f);

#pragma unroll
    for (int ch = 0; ch < 4; ++ch) {
        const int dB = ch * 128;
#pragma unroll
        for (int q = 0; q < 2; ++q) {
            const int s  = tid + 256 * q;
            const int r  = s >> 2;
            const int c4 = (s & 3) * 4;
            const float4 v = *reinterpret_cast<const float4*>(
                &A[(size_t)(dB + r) * M_DIM + mB + c4]);
            tile[r][c4]     = v.x;
            tile[r][c4 + 1] = v.y;
            tile[r][c4 + 2] = v.z;
            tile[r][c4 + 3] = v.w;
        }
        __syncthreads();
        {
            const int m  = tid >> 4;
            const int d8 = (tid & 15) * 8;
            const float sc = inv[m];
            uint4 p;
            p.x = (unsigned)f2bf(tile[d8 + 0][m] * sc) | ((unsigned)f2bf(tile[d8 + 1][m] * sc) << 16);
            p.y = (unsigned)f2bf(tile[d8 + 2][m] * sc) | ((unsigned)f2bf(tile[d8 + 3][m] * sc) << 16);
            p.z = (unsigned)f2bf(tile[d8 + 4][m] * sc) | ((unsigned)f2bf(tile[d8 + 5][m] * sc) << 16);
            p.w = (unsigned)f2bf(tile[d8 + 6][m] * sc) | ((unsigned)f2bf(tile[d8 + 7][m] * sc) << 16);
            *reinterpret_cast<uint4*>(&ant[(size_t)(mB + m) * D_DIM + dB + d8]) = p;
        }
        __syncthreads();
    }
}

// ---------- K2: fused GEMM+CF, BK=128 (8 barriers vs 16), plain store (R17) ----------
// Tile 128 b x 32 m; grid (32 m, 32 t) = 1024 blocks; LDS exactly 40960 B -> 4 blk/CU.
// Rows now 256 B: XOR-granule swizzle g ^= (row&15); aliased pairs (g,g+8) = 2-way (free).
// MFMA sequence identical to R17 (same K order) -> bit-identical numerics.
#define CHEB(CS) { const f32x2 nxt = c2 * cur - prev; prev = cur; cur = nxt; CS += cur; }
#define CF_ALL(V) { \
    float s1, c1; fast_sincos((V) * DT, s1, c1); \
    const float c2 = 2.0f * c1; \
    f32x2 prev = {1.0f, 0.0f}; \
    f32x2 cur  = {c1, s1}; \
    cs0 += cur; \
    CHEB(cs1)  CHEB(cs2)  CHEB(cs3)  CHEB(cs4)  CHEB(cs5) \
    CHEB(cs6)  CHEB(cs7)  CHEB(cs8)  CHEB(cs9)  CHEB(cs10) \
    CHEB(cs11) CHEB(cs12) CHEB(cs13) CHEB(cs14) CHEB(cs15) }
#define RED(CS) { \
    CS.x += __shfl_xor(CS.x, 16); CS.x += __shfl_xor(CS.x, 32); \
    CS.y += __shfl_xor(CS.y, 16); CS.y += __shfl_xor(CS.y, 32); }
#define ST(CS, K) { wred[wc][l15][K] = CS.x; wred[wc][l15][16 + K] = CS.y; }
#define FIN(CS, KK) { \
    constexpr float tk = DT * (float)(KK); \
    const float g  = __expf(-0.5f * tk * tk); \
    const float w  = (((KK) == 16) ? DT : 2.0f * DT) * g; \
    const float totC = wred[wc][l15][(KK) - 1]      + CS.x; \
    const float totS = wred[wc][l15][16 + (KK) - 1] + CS.y; \
    const float cm = fmaf(totC, invB, -g); \
    const float sm = totS * invB; \
    s = fmaf(w, fmaf(cm, cm, sm * sm), s); }

__global__ __launch_bounds__(256) void fused_kernel(const ushort* __restrict__ zb,
                                                    const ushort* __restrict__ ant,
                                                    float* __restrict__ partials) {
    // As (32 KB) unioned with the CF-reduce scratch (used strictly after the K-loop's
    // final barrier). Total LDS = 32768 + 8192 = 40960 B exactly -> 4 blocks/CU.
    __shared__ __align__(16) union SharedU {
        ushort As[128 * 128];
        struct { float wred[2][16][33]; float bred[2]; } r;
    } u;
    __shared__ __align__(16) ushort Bs[32 * 128];

    const int tid  = threadIdx.x;
    const int mB   = blockIdx.x * 32;               // 32 m-blocks
    const int t    = blockIdx.y;                    // 0..31
    const int wave = tid >> 6;
    const int lane = tid & 63;
    const int wr   = wave >> 1;                     // b-row half
    const int wc   = wave & 1;                      // m-col half
    const int l15  = lane & 15;
    const int lhi  = lane >> 4;

    // staging: each gload16 covers 4 rows x 16 granules(16B). row = r0 + lane>>4;
    // source granule pre-swizzled: gs = (lane&15) ^ (row&15).
    const int rofs = lane >> 4;                     // 0..3
    const int gl   = lane & 15;

    const ushort* zrow = zb + (size_t)t * B_DIM * D_DIM;

    f32x4 acc[4];
#pragma unroll
    for (int fm = 0; fm < 4; ++fm) acc[fm] = (f32x4)(0.0f);

#pragma unroll
    for (int it = 0; it < 4; ++it) {
        const int k0 = it * 128;
        // stage A: 32 gload16 (8/wave); B: 8 gload16 (2/wave)
#pragma unroll
        for (int j = 0; j < 8; ++j) {
            const int r0  = wave * 32 + j * 4;
            const int row = r0 + rofs;
            const int gs  = gl ^ (row & 15);
            gload16(&zrow[(size_t)row * D_DIM + k0 + gs * 8], &u.As[r0 * 128]);
        }
#pragma unroll
        for (int j = 0; j < 2; ++j) {
            const int r0  = wave * 8 + j * 4;
            const int row = r0 + rofs;
            const int gs  = gl ^ (row & 15);
            gload16(&ant[(size_t)(mB + row) * D_DIM + k0 + gs * 8], &Bs[r0 * 128]);
        }
        __syncthreads();                   // drains vmcnt -> LDS visible

#pragma unroll
        for (int ks = 0; ks < 4; ++ks) {
            const int gd = (ks * 4 + lhi) ^ l15;    // swizzled granule (rows&15 == l15)
            const int co = gd * 8;                  // ushort offset within row
            const bf16x8 bfrag = *reinterpret_cast<const bf16x8*>(&Bs[(wc * 16 + l15) * 128 + co]);
#pragma unroll
            for (int fm = 0; fm < 4; ++fm) {
                const bf16x8 afrag = *reinterpret_cast<const bf16x8*>(&u.As[(wr * 64 + fm * 16 + l15) * 128 + co]);
                acc[fm] = __builtin_amdgcn_mfma_f32_16x16x32_bf16(afrag, bfrag, acc[fm], 0, 0, 0);
            }
        }
        __syncthreads();                   // readers done before overwrite / union reuse
    }

    float (&wred)[2][16][33] = u.r.wred;   // As region is dead past the final barrier
    float (&bred)[2] = u.r.bred;

    // ---- CF: per lane m = mB + wc*16 + l15 fixed; 16 b-values in acc (validated) ----
    f32x2 cs0  = {0.f, 0.f}, cs1  = {0.f, 0.f}, cs2  = {0.f, 0.f}, cs3  = {0.f, 0.f};
    f32x2 cs4  = {0.f, 0.f}, cs5  = {0.f, 0.f}, cs6  = {0.f, 0.f}, cs7  = {0.f, 0.f};
    f32x2 cs8  = {0.f, 0.f}, cs9  = {0.f, 0.f}, cs10 = {0.f, 0.f}, cs11 = {0.f, 0.f};
    f32x2 cs12 = {0.f, 0.f}, cs13 = {0.f, 0.f}, cs14 = {0.f, 0.f}, cs15 = {0.f, 0.f};

#pragma unroll
    for (int fm = 0; fm < 4; ++fm) {
        const f32x4 av = acc[fm];
        CF_ALL(av.x) CF_ALL(av.y) CF_ALL(av.z) CF_ALL(av.w)
    }

    RED(cs0)  RED(cs1)  RED(cs2)  RED(cs3)  RED(cs4)  RED(cs5)  RED(cs6)  RED(cs7)
    RED(cs8)  RED(cs9)  RED(cs10) RED(cs11) RED(cs12) RED(cs13) RED(cs14) RED(cs15)

    if (wr == 0 && lane < 16) {
        ST(cs0, 0)   ST(cs1, 1)   ST(cs2, 2)   ST(cs3, 3)
        ST(cs4, 4)   ST(cs5, 5)   ST(cs6, 6)   ST(cs7, 7)
        ST(cs8, 8)   ST(cs9, 9)   ST(cs10, 10) ST(cs11, 11)
        ST(cs12, 12) ST(cs13, 13) ST(cs14, 14) ST(cs15, 15)
    }
    __syncthreads();

    if (wr == 1) {
        const float invB = 1.0f / 128.0f;
        float s = 0.0f;
        FIN(cs0, 1)   FIN(cs1, 2)   FIN(cs2, 3)   FIN(cs3, 4)
        FIN(cs4, 5)   FIN(cs5, 6)   FIN(cs6, 7)   FIN(cs7, 8)
        FIN(cs8, 9)   FIN(cs9, 10)  FIN(cs10, 11) FIN(cs11, 12)
        FIN(cs12, 13) FIN(cs13, 14) FIN(cs14, 15) FIN(cs15, 16)
        // butterfly over 64 lanes: each l15 column counted 4x (lhi copies)
#pragma unroll
        for (int m = 1; m < 64; m <<= 1) s += __shfl_xor(s, m);
        if (lane == 0) bred[wc] = s;
    }
    __syncthreads();
    // plain uncontended store (atomic tail removed in R17: -7.3 us); scale in finalize
    if (tid == 0)
        partials[blockIdx.y * 32 + blockIdx.x] = bred[0] + bred[1];
}

// ---------- K3: final reduce of 1024 partials ----------
// out = sum(partials) * (0.25 dup) * 128 / (T*M) = sum / 1024
__global__ __launch_bounds__(256) void finalize_kernel(const float* __restrict__ partials,
                                                       float* __restrict__ out) {
    __shared__ float red[256];
    const int tid = threadIdx.x;
    red[tid] = partials[tid] + partials[tid + 256] + partials[tid + 512] + partials[tid + 768];
    __syncthreads();
    for (int s = 128; s > 0; s >>= 1) {
        if (tid < s) red[tid] += red[tid + s];
        __syncthreads();
    }
    if (tid == 0) out[0] = red[0] * (1.0f / 1024.0f);
}

extern "C" void kernel_launch(void* const* d_in, const int* in_sizes, int n_in,
                              void* d_out, int out_size, void* d_ws, size_t ws_size,
                              hipStream_t stream) {
    const float* z = (const float*)d_in[0];   // (32,128,512)
    const float* A = (const float*)d_in[1];   // (512,1024)
    float* out = (float*)d_out;

    char* ws = (char*)d_ws;
    ushort* zb       = (ushort*)ws;                        // 4 MB
    ushort* ant      = (ushort*)(ws + 4 * 1024 * 1024);    // 1 MB
    float*  partials = (float*)(ws + 5 * 1024 * 1024);     // 4 KB

    prep_kernel<<<576, 256, 0, stream>>>(A, z, zb, ant);
    fused_kernel<<<dim3(M_DIM / 32, T_DIM), 256, 0, stream>>>(zb, ant, partials);
    finalize_kernel<<<1, 256, 0, stream>>>(partials, out);
}

// Round 19
// 31.005 us; speedup vs baseline: 1.4132x; 1.0189x over previous
//
#include <hip/hip_runtime.h>
#include <hip/hip_bf16.h>
#include <math.h>

#define T_DIM 32
#define B_DIM 128
#define D_DIM 512
#define M_DIM 1024

constexpr float DT = 0.1875f;          // 3.0 / 16
constexpr float INV_2PI = 0.15915494309189535f;

typedef __attribute__((ext_vector_type(8))) short bf16x8;   // 8 bf16 = 4 VGPR
typedef __attribute__((ext_vector_type(4))) float f32x4;    // MFMA acc
typedef __attribute__((ext_vector_type(2))) float f32x2;    // packed (cos,sin)

__device__ __forceinline__ ushort f2bf(float f) {           // RNE fp32->bf16
    unsigned u = __float_as_uint(f);
    u += 0x7FFFu + ((u >> 16) & 1u);
    return (ushort)(u >> 16);
}

// async global->LDS, 16B per lane; LDS dest is wave-uniform base + lane*16.
__device__ __forceinline__ void gload16(const void* g, void* l) {
    __builtin_amdgcn_global_load_lds(
        (const __attribute__((address_space(1))) void*)g,
        (__attribute__((address_space(3))) void*)l, 16, 0, 0);
}

// v_sin/v_cos take REVOLUTIONS (ISA: D=sin(S0*2pi)); reduce with floor.
__device__ __forceinline__ void fast_sincos(float theta, float& s, float& c) {
    float r = theta * INV_2PI;
    r -= floorf(r);
    s = __builtin_amdgcn_sinf(r);
    c = __builtin_amdgcn_cosf(r);
}

// ---------- K1: prep (validated R8-R18). blocks 0..63: colnorm+transpose -> ant.
//                blocks 64..575: z -> bf16. ----------
__global__ __launch_bounds__(256) void prep_kernel(const float* __restrict__ A,
                                                   const float* __restrict__ z,
                                                   ushort* __restrict__ zb,
                                                   ushort* __restrict__ ant) {
    const int bid = blockIdx.x;
    const int tid = threadIdx.x;

    if (bid >= 64) {                       // ---- zconv: 512 blocks x 4096 floats ----
        const size_t base = (size_t)(bid - 64) * 4096 + tid * 8;
#pragma unroll
        for (int j = 0; j < 2; ++j) {
            const size_t i = base + j * 2048;
            const float4 a = *reinterpret_cast<const float4*>(&z[i]);
            const float4 b = *reinterpret_cast<const float4*>(&z[i + 4]);
            uint4 p;
            p.x = (unsigned)f2bf(a.x) | ((unsigned)f2bf(a.y) << 16);
            p.y = (unsigned)f2bf(a.z) | ((unsigned)f2bf(a.w) << 16);
            p.z = (unsigned)f2bf(b.x) | ((unsigned)f2bf(b.y) << 16);
            p.w = (unsigned)f2bf(b.z) | ((unsigned)f2bf(b.w) << 16);
            *reinterpret_cast<uint4*>(&zb[i]) = p;
        }
        return;
    }

    __shared__ float red[256];
    __shared__ float inv[16];
    __shared__ float tile[128][17];

    const int mB = bid * 16;
    const int mo = tid & 15;
    const int dg = tid >> 4;
    float ss = 0.0f;
#pragma unroll 4
    for (int i = 0; i < 32; ++i) {
        const float v = A[(size_t)(dg * 32 + i) * M_DIM + mB + mo];
        ss = fmaf(v, v, ss);
    }
    red[tid] = ss;
    __syncthreads();
    for (int s = 128; s >= 16; s >>= 1) {
        if (tid < s) red[tid] += red[tid + s];
        __syncthreads();
    }
    if (tid < 16) inv[tid] = 1.0f / fmaxf(sqrtf(red[tid]), 1e-12f);

#pragma unroll
    for (int ch = 0; ch < 4; ++ch) {
        const int dB = ch * 128;
#pragma unroll
        for (int q = 0; q < 2; ++q) {
            const int s  = tid + 256 * q;
            const int r  = s >> 2;
            const int c4 = (s & 3) * 4;
            const float4 v = *reinterpret_cast<const float4*>(
                &A[(size_t)(dB + r) * M_DIM + mB + c4]);
            tile[r][c4]     = v.x;
            tile[r][c4 + 1] = v.y;
            tile[r][c4 + 2] = v.z;
            tile[r][c4 + 3] = v.w;
        }
        __syncthreads();
        {
            const int m  = tid >> 4;
            const int d8 = (tid & 15) * 8;
            const float sc = inv[m];
            uint4 p;
            p.x = (unsigned)f2bf(tile[d8 + 0][m] * sc) | ((unsigned)f2bf(tile[d8 + 1][m] * sc) << 16);
            p.y = (unsigned)f2bf(tile[d8 + 2][m] * sc) | ((unsigned)f2bf(tile[d8 + 3][m] * sc) << 16);
            p.z = (unsigned)f2bf(tile[d8 + 4][m] * sc) | ((unsigned)f2bf(tile[d8 + 5][m] * sc) << 16);
            p.w = (unsigned)f2bf(tile[d8 + 6][m] * sc) | ((unsigned)f2bf(tile[d8 + 7][m] * sc) << 16);
            *reinterpret_cast<uint4*>(&ant[(size_t)(mB + m) * D_DIM + dB + d8]) = p;
        }
        __syncthreads();
    }
}

// ---------- K2: fused GEMM+CF, tile 128b x 64m, 8 waves (2x4), BK=128 ----------
// Halves zb L2 re-reads (16 blocks/t-slice) and raises TLP to 3 blk/CU x 8 waves
// = 24 waves/CU. Same validated swizzle (R13/R18), CF chain (R4), plain-store (R17).
#define CHEB(CS) { const f32x2 nxt = c2 * cur - prev; prev = cur; cur = nxt; CS += cur; }
#define CF_ALL(V) { \
    float s1, c1; fast_sincos((V) * DT, s1, c1); \
    const float c2 = 2.0f * c1; \
    f32x2 prev = {1.0f, 0.0f}; \
    f32x2 cur  = {c1, s1}; \
    cs0 += cur; \
    CHEB(cs1)  CHEB(cs2)  CHEB(cs3)  CHEB(cs4)  CHEB(cs5) \
    CHEB(cs6)  CHEB(cs7)  CHEB(cs8)  CHEB(cs9)  CHEB(cs10) \
    CHEB(cs11) CHEB(cs12) CHEB(cs13) CHEB(cs14) CHEB(cs15) }
#define RED(CS) { \
    CS.x += __shfl_xor(CS.x, 16); CS.x += __shfl_xor(CS.x, 32); \
    CS.y += __shfl_xor(CS.y, 16); CS.y += __shfl_xor(CS.y, 32); }
#define ST(CS, K) { wred[wc][l15][K] = CS.x; wred[wc][l15][16 + K] = CS.y; }
#define FIN(CS, KK) { \
    constexpr float tk = DT * (float)(KK); \
    const float g  = __expf(-0.5f * tk * tk); \
    const float w  = (((KK) == 16) ? DT : 2.0f * DT) * g; \
    const float totC = wred[wc][l15][(KK) - 1]      + CS.x; \
    const float totS = wred[wc][l15][16 + (KK) - 1] + CS.y; \
    const float cm = fmaf(totC, invB, -g); \
    const float sm = totS * invB; \
    s = fmaf(w, fmaf(cm, cm, sm * sm), s); }

__global__ __launch_bounds__(512) void fused_kernel(const ushort* __restrict__ zb,
                                                    const ushort* __restrict__ ant,
                                                    float* __restrict__ partials) {
    // As (32 KB) unioned with CF-reduce scratch (used strictly after final K barrier).
    // Total LDS = 32768 + 16384 = 49152 B -> 3 blocks/CU, 24 waves/CU.
    __shared__ __align__(16) union SharedU {
        ushort As[128 * 128];
        struct { float wred[4][16][33]; float bred[4]; } r;
    } u;
    __shared__ __align__(16) ushort Bs[64 * 128];

    const int tid  = threadIdx.x;
    const int mB   = blockIdx.x * 64;               // 16 m-blocks
    const int t    = blockIdx.y;                    // 0..31
    const int wave = tid >> 6;                      // 0..7
    const int lane = tid & 63;
    const int wr   = wave >> 2;                     // 0..1  b-row half
    const int wc   = wave & 3;                      // 0..3  m-col quarter (16 cols)
    const int l15  = lane & 15;
    const int lhi  = lane >> 4;

    // staging: each gload16 covers 4 rows x 16 granules(16B); source pre-swizzled.
    const int rofs = lane >> 4;                     // 0..3
    const int gl   = lane & 15;

    const ushort* zrow = zb + (size_t)t * B_DIM * D_DIM;

    f32x4 acc[4];
#pragma unroll
    for (int fm = 0; fm < 4; ++fm) acc[fm] = (f32x4)(0.0f);

#pragma unroll
    for (int it = 0; it < 4; ++it) {
        const int k0 = it * 128;
        // stage A: 32 gload16 (4/wave); B: 16 gload16 (2/wave)
#pragma unroll
        for (int j = 0; j < 4; ++j) {
            const int r0  = wave * 16 + j * 4;
            const int row = r0 + rofs;
            const int gs  = gl ^ (row & 15);
            gload16(&zrow[(size_t)row * D_DIM + k0 + gs * 8], &u.As[r0 * 128]);
        }
#pragma unroll
        for (int j = 0; j < 2; ++j) {
            const int r0  = wave * 8 + j * 4;
            const int row = r0 + rofs;
            const int gs  = gl ^ (row & 15);
            gload16(&ant[(size_t)(mB + row) * D_DIM + k0 + gs * 8], &Bs[r0 * 128]);
        }
        __syncthreads();                   // drains vmcnt -> LDS visible

#pragma unroll
        for (int ks = 0; ks < 4; ++ks) {
            const int gd = (ks * 4 + lhi) ^ l15;    // swizzled granule (row&15 == l15)
            const int co = gd * 8;
            const bf16x8 bfrag = *reinterpret_cast<const bf16x8*>(&Bs[(wc * 16 + l15) * 128 + co]);
#pragma unroll
            for (int fm = 0; fm < 4; ++fm) {
                const bf16x8 afrag = *reinterpret_cast<const bf16x8*>(&u.As[(wr * 64 + fm * 16 + l15) * 128 + co]);
                acc[fm] = __builtin_amdgcn_mfma_f32_16x16x32_bf16(afrag, bfrag, acc[fm], 0, 0, 0);
            }
        }
        __syncthreads();                   // readers done before overwrite / union reuse
    }

    float (&wred)[4][16][33] = u.r.wred;   // As region dead past final barrier
    float (&bred)[4] = u.r.bred;

    // ---- CF: per lane m = mB + wc*16 + l15 fixed; 16 b-values in acc (validated) ----
    f32x2 cs0  = {0.f, 0.f}, cs1  = {0.f, 0.f}, cs2  = {0.f, 0.f}, cs3  = {0.f, 0.f};
    f32x2 cs4  = {0.f, 0.f}, cs5  = {0.f, 0.f}, cs6  = {0.f, 0.f}, cs7  = {0.f, 0.f};
    f32x2 cs8  = {0.f, 0.f}, cs9  = {0.f, 0.f}, cs10 = {0.f, 0.f}, cs11 = {0.f, 0.f};
    f32x2 cs12 = {0.f, 0.f}, cs13 = {0.f, 0.f}, cs14 = {0.f, 0.f}, cs15 = {0.f, 0.f};

#pragma unroll
    for (int fm = 0; fm < 4; ++fm) {
        const f32x4 av = acc[fm];
        CF_ALL(av.x) CF_ALL(av.y) CF_ALL(av.z) CF_ALL(av.w)
    }

    // fold the wave's 4 lhi copies of each column (wave covers 64 b-rows)
    RED(cs0)  RED(cs1)  RED(cs2)  RED(cs3)  RED(cs4)  RED(cs5)  RED(cs6)  RED(cs7)
    RED(cs8)  RED(cs9)  RED(cs10) RED(cs11) RED(cs12) RED(cs13) RED(cs14) RED(cs15)

    if (wr == 0 && lane < 16) {            // waves 0..3 (wc = 0..3)
        ST(cs0, 0)   ST(cs1, 1)   ST(cs2, 2)   ST(cs3, 3)
        ST(cs4, 4)   ST(cs5, 5)   ST(cs6, 6)   ST(cs7, 7)
        ST(cs8, 8)   ST(cs9, 9)   ST(cs10, 10) ST(cs11, 11)
        ST(cs12, 12) ST(cs13, 13) ST(cs14, 14) ST(cs15, 15)
    }
    __syncthreads();

    float s = 0.0f;
    if (wr == 1) {                         // waves 4..7 (wc = 0..3)
        const float invB = 1.0f / 128.0f;
        FIN(cs0, 1)   FIN(cs1, 2)   FIN(cs2, 3)   FIN(cs3, 4)
        FIN(cs4, 5)   FIN(cs5, 6)   FIN(cs6, 7)   FIN(cs7, 8)
        FIN(cs8, 9)   FIN(cs9, 10)  FIN(cs10, 11) FIN(cs11, 12)
        FIN(cs12, 13) FIN(cs13, 14) FIN(cs14, 15) FIN(cs15, 16)
        // butterfly over 64 lanes: each l15 column counted 4x (lhi copies)
#pragma unroll
        for (int m = 1; m < 64; m <<= 1) s += __shfl_xor(s, m);
        if (lane == 0) bred[wc] = s;
    }
    __syncthreads();
    // plain uncontended store; combined scale folded into finalize (sum/1024, as before)
    if (tid == 0)
        partials[blockIdx.y * 16 + blockIdx.x] = bred[0] + bred[1] + bred[2] + bred[3];
}

// ---------- K3: final reduce of 512 partials ----------
// out = sum(partials) * (0.25 dup) * 128 / (T*M) = sum / 1024
__global__ __launch_bounds__(256) void finalize_kernel(const float* __restrict__ partials,
                                                       float* __restrict__ out) {
    __shared__ float red[256];
    const int tid = threadIdx.x;
    red[tid] = partials[tid] + partials[tid + 256];
    __syncthreads();
    for (int s = 128; s > 0; s >>= 1) {
        if (tid < s) red[tid] += red[tid + s];
        __syncthreads();
    }
    if (tid == 0) out[0] = red[0] * (1.0f / 1024.0f);
}

extern "C" void kernel_launch(void* const* d_in, const int* in_sizes, int n_in,
                              void* d_out, int out_size, void* d_ws, size_t ws_size,
                              hipStream_t stream) {
    const float* z = (const float*)d_in[0];   // (32,128,512)
    const float* A = (const float*)d_in[1];   // (512,1024)
    float* out = (float*)d_out;

    char* ws = (char*)d_ws;
    ushort* zb       = (ushort*)ws;                        // 4 MB
    ushort* ant      = (ushort*)(ws + 4 * 1024 * 1024);    // 1 MB
    float*  partials = (float*)(ws + 5 * 1024 * 1024);     // 2 KB

    prep_kernel<<<576, 256, 0, stream>>>(A, z, zb, ant);
    fused_kernel<<<dim3(M_DIM / 64, T_DIM), 512, 0, stream>>>(zb, ant, partials);
    finalize_kernel<<<1, 256, 0, stream>>>(partials, out);
}